// Round 2
// baseline (533.688 us; speedup 1.0000x reference)
//
#include <hip/hip_runtime.h>

// Causal linear attention (Performer ReLU kernel), chunked-scan formulation.
// B=2 L=4096 H=8 D=64 M=256, fp32. Chunk T=128, C=32 chunks, NBH=16 heads.
// Round 2: 512-thread blocks, lane-paired D-split (preg/Sreg/kv = 32 regs),
// barrier-light phase3 (intra-wave qp/kp sharing; deferred num/den reduce).
// ws layout: S [NBH][C][M*D] (32 MB) then Z [NBH][C][M] (0.5 MB).

#define B_   2
#define L_   4096
#define H_   8
#define D_   64
#define M_   256
#define T_   128
#define C_   (L_ / T_)   // 32
#define NBH  (B_ * H_)   // 16
#define RATIO 0.0625f    // 1/sqrt(M)
#define STAB  0.001f

#define TS1  32          // phase1 staging sub-tile
#define TS3  16          // phase3 sub-tile (bounded by numP LDS)

// ---------------- Phase 1: per-chunk K-feature sums ----------------
// 512 threads. Lane pair (2t,2t+1) owns feature m = w*32 + lane/2; each lane
// handles d-half dh = lane&1 (32 elems of proj row and S row in regs).
__global__ __launch_bounds__(512, 4)
void phase1_kernel(const float* __restrict__ key, const float* __restrict__ val,
                   const float* __restrict__ proj,
                   float* __restrict__ S, float* __restrict__ Z) {
    const int c = blockIdx.x, bh = blockIdx.y;
    const int b = bh / H_, h = bh % H_;
    const int tid = threadIdx.x;
    const int w = tid >> 6, lane = tid & 63;
    const int m = w * 32 + (lane >> 1);
    const int dh = lane & 1;

    __shared__ float kT[TS1 * D_];
    __shared__ float vT[TS1 * D_];

    float preg[32];
    {
        const float4* p4 = (const float4*)(proj + (size_t)m * D_ + dh * 32);
#pragma unroll
        for (int i = 0; i < 8; ++i) {
            float4 t = p4[i];
            preg[4*i]=t.x; preg[4*i+1]=t.y; preg[4*i+2]=t.z; preg[4*i+3]=t.w;
        }
    }
    float Sreg[32];
#pragma unroll
    for (int i = 0; i < 32; ++i) Sreg[i] = 0.f;
    float zreg = 0.f;

    const size_t base = ((size_t)b * L_ + (size_t)c * T_) * (H_ * D_) + (size_t)h * D_;

    for (int t0 = 0; t0 < T_; t0 += TS1) {
        __syncthreads();
        {   // 512 float4 per array, exactly 1 per thread per array
            int ls = tid >> 4, dd = tid & 15;
            size_t g = base + (size_t)(t0 + ls) * (H_ * D_) + (size_t)dd * 4;
            *(float4*)(&kT[ls * D_ + dd * 4]) = *(const float4*)(key + g);
            *(float4*)(&vT[ls * D_ + dd * 4]) = *(const float4*)(val + g);
        }
        __syncthreads();

        for (int ls = 0; ls < TS1; ++ls) {
            const float4* kr = (const float4*)(&kT[ls * D_ + dh * 32]);
            float a0=0.f,a1=0.f,a2=0.f,a3=0.f;
#pragma unroll
            for (int i = 0; i < 8; ++i) {
                float4 k4 = kr[i];
                a0 = fmaf(preg[4*i],   k4.x, a0);
                a1 = fmaf(preg[4*i+1], k4.y, a1);
                a2 = fmaf(preg[4*i+2], k4.z, a2);
                a3 = fmaf(preg[4*i+3], k4.w, a3);
            }
            float pk = (a0 + a1) + (a2 + a3);
            pk += __shfl_xor(pk, 1, 64);            // combine d-halves (pair)
            float kp = fmaxf(RATIO * pk, 0.f) + STAB;
            zreg += kp;
            const float4* vr = (const float4*)(&vT[ls * D_ + dh * 32]);
#pragma unroll
            for (int i = 0; i < 8; ++i) {
                float4 v4 = vr[i];
                Sreg[4*i]   = fmaf(kp, v4.x, Sreg[4*i]);
                Sreg[4*i+1] = fmaf(kp, v4.y, Sreg[4*i+1]);
                Sreg[4*i+2] = fmaf(kp, v4.z, Sreg[4*i+2]);
                Sreg[4*i+3] = fmaf(kp, v4.w, Sreg[4*i+3]);
            }
        }
    }

    float* Sout = S + (size_t)(bh * C_ + c) * (M_ * D_) + (size_t)m * D_ + dh * 32;
#pragma unroll
    for (int i = 0; i < 8; ++i) {
        float4 t; t.x=Sreg[4*i]; t.y=Sreg[4*i+1]; t.z=Sreg[4*i+2]; t.w=Sreg[4*i+3];
        ((float4*)Sout)[i] = t;
    }
    if (dh == 0) Z[(size_t)(bh * C_ + c) * M_ + m] = zreg;
}

// ---------------- Phase 2: exclusive prefix over chunks (in place) --------
__global__ void phase2_kernel(float* __restrict__ S, float* __restrict__ Z) {
    const int bh = blockIdx.y;
    const int j = blockIdx.x * 256 + threadIdx.x;
    if (j < M_ * D_) {
        float run = 0.f;
        float* p = S + (size_t)bh * C_ * M_ * D_ + j;
        for (int c = 0; c < C_; ++c) {
            float t = p[(size_t)c * (M_ * D_)];
            p[(size_t)c * (M_ * D_)] = run;
            run += t;
        }
    } else {
        const int j2 = j - M_ * D_;
        if (j2 < M_) {
            float run = 0.f;
            float* p = Z + (size_t)bh * C_ * M_ + j2;
            for (int c = 0; c < C_; ++c) {
                float t = p[c * M_];
                p[c * M_] = run;
                run += t;
            }
        }
    }
}

// ---------------- Phase 3: within-chunk scan seeded from prefix ----------
// 512 threads, 8 waves. Wave w owns kv[m in 32w..32w+32) at d=lane (32 regs).
// Lane pair owns feature m = 32w + lane/2 for projections (preg 32 regs).
// qp/kp sharing is INTRA-WAVE (LDS, no barrier). num/den reduced across waves
// once per TS3 sub-tile via per-wave partials.
__global__ __launch_bounds__(512, 4)
void phase3_kernel(const float* __restrict__ q, const float* __restrict__ key,
                   const float* __restrict__ val, const float* __restrict__ proj,
                   const float* __restrict__ S, const float* __restrict__ Z,
                   float* __restrict__ out) {
    const int c = blockIdx.x, bh = blockIdx.y;
    const int b = bh / H_, h = bh % H_;
    const int tid = threadIdx.x;
    const int w = tid >> 6, lane = tid & 63;
    const int m = w * 32 + (lane >> 1);
    const int dh = lane & 1;

    __shared__ float qT[TS3 * D_];
    __shared__ float kT[TS3 * D_];
    __shared__ float vT[TS3 * D_];
    __shared__ float qpS[M_];
    __shared__ float kpS[M_];
    __shared__ float numP[8][TS3][D_];   // per-wave numerator partials (32 KB)
    __shared__ float denP[8][TS3];       // per-wave denominator partials

    float preg[32];
    {
        const float4* p4 = (const float4*)(proj + (size_t)m * D_ + dh * 32);
#pragma unroll
        for (int i = 0; i < 8; ++i) {
            float4 t = p4[i];
            preg[4*i]=t.x; preg[4*i+1]=t.y; preg[4*i+2]=t.z; preg[4*i+3]=t.w;
        }
    }

    // seed kv state from exclusive prefix: kv[i] = Sbar[32w+i][lane]
    const float* Sp = S + (size_t)(bh * C_ + c) * (M_ * D_);
    float kv[32];
#pragma unroll
    for (int i = 0; i < 32; ++i) kv[i] = Sp[(size_t)(32 * w + i) * D_ + lane];
    float zc = Z[(size_t)(bh * C_ + c) * M_ + m];   // both pair lanes: same value

    const size_t base = ((size_t)b * L_ + (size_t)c * T_) * (H_ * D_) + (size_t)h * D_;

    for (int t0 = 0; t0 < T_; t0 += TS3) {
        __syncthreads();   // prev sub-tile reduce done; safe to restage
        for (int r = tid; r < 3 * TS3 * 16; r += 512) {   // 768 float4
            int arr = r >> 8;        // 0:q 1:k 2:v
            int idx = r & 255;
            int ls = idx >> 4, dd = idx & 15;
            size_t g = base + (size_t)(t0 + ls) * (H_ * D_) + (size_t)dd * 4;
            const float* src = (arr == 0) ? q : (arr == 1) ? key : val;
            float* dst = (arr == 0) ? qT : (arr == 1) ? kT : vT;
            *(float4*)(&dst[ls * D_ + dd * 4]) = *(const float4*)(src + g);
        }
        __syncthreads();

        for (int ls = 0; ls < TS3; ++ls) {
            // projections for feature m (d-half per lane)
            const float4* qr = (const float4*)(&qT[ls * D_ + dh * 32]);
            const float4* kr = (const float4*)(&kT[ls * D_ + dh * 32]);
            float qa0=0.f,qa1=0.f,qa2=0.f,qa3=0.f, ka0=0.f,ka1=0.f,ka2=0.f,ka3=0.f;
#pragma unroll
            for (int i = 0; i < 8; ++i) {
                float4 q4 = qr[i]; float4 k4 = kr[i];
                qa0 = fmaf(preg[4*i],   q4.x, qa0); ka0 = fmaf(preg[4*i],   k4.x, ka0);
                qa1 = fmaf(preg[4*i+1], q4.y, qa1); ka1 = fmaf(preg[4*i+1], k4.y, ka1);
                qa2 = fmaf(preg[4*i+2], q4.z, qa2); ka2 = fmaf(preg[4*i+2], k4.z, ka2);
                qa3 = fmaf(preg[4*i+3], q4.w, qa3); ka3 = fmaf(preg[4*i+3], k4.w, ka3);
            }
            float pq = (qa0+qa1)+(qa2+qa3);
            float pk = (ka0+ka1)+(ka2+ka3);
            pq += __shfl_xor(pq, 1, 64);
            pk += __shfl_xor(pk, 1, 64);
            float qp = fmaxf(RATIO * pq, 0.f) + STAB;
            float kp = fmaxf(RATIO * pk, 0.f) + STAB;
            zc += kp;
            if (dh == 0) { qpS[m] = qp; kpS[m] = kp; }   // intra-wave share
            float dpart = dh ? 0.f : qp * zc;
            dpart += __shfl_xor(dpart, 32, 64);
            dpart += __shfl_xor(dpart, 16, 64);
            dpart += __shfl_xor(dpart,  8, 64);
            dpart += __shfl_xor(dpart,  4, 64);
            dpart += __shfl_xor(dpart,  2, 64);
            dpart += __shfl_xor(dpart,  1, 64);
            if (lane == 0) denP[w][ls] = dpart;

            // kv update + numerator partial for d=lane over own m-slice
            float vreg = vT[ls * D_ + lane];
            const float4* kp4 = (const float4*)(&kpS[w * 32]);
            const float4* qp4 = (const float4*)(&qpS[w * 32]);
            float n0=0.f, n1=0.f, n2=0.f, n3=0.f;
#pragma unroll
            for (int i = 0; i < 8; ++i) {
                float4 kk4 = kp4[i]; float4 qq4 = qp4[i];
                kv[4*i]   = fmaf(kk4.x, vreg, kv[4*i]);   n0 = fmaf(qq4.x, kv[4*i],   n0);
                kv[4*i+1] = fmaf(kk4.y, vreg, kv[4*i+1]); n1 = fmaf(qq4.y, kv[4*i+1], n1);
                kv[4*i+2] = fmaf(kk4.z, vreg, kv[4*i+2]); n2 = fmaf(qq4.z, kv[4*i+2], n2);
                kv[4*i+3] = fmaf(kk4.w, vreg, kv[4*i+3]); n3 = fmaf(qq4.w, kv[4*i+3], n3);
            }
            numP[w][ls][lane] = (n0 + n1) + (n2 + n3);
        }
        __syncthreads();   // all partials visible

        // reduce 8 wave-partials and write TS3*64 outputs
        for (int o = tid; o < TS3 * D_; o += 512) {
            int ls = o >> 6, d = o & 63;
            float num = 0.f, den = 0.f;
#pragma unroll
            for (int ww = 0; ww < 8; ++ww) {
                num += numP[ww][ls][d];
                den += denP[ww][ls];
            }
            if (den <= 0.f) den = 1.f;
            int l = c * T_ + t0 + ls;
            out[((size_t)(b * L_ + l) * H_ + h) * D_ + d] = num / den;
        }
    }
}

extern "C" void kernel_launch(void* const* d_in, const int* in_sizes, int n_in,
                              void* d_out, int out_size, void* d_ws, size_t ws_size,
                              hipStream_t stream) {
    const float* q    = (const float*)d_in[0];
    const float* k    = (const float*)d_in[1];
    const float* v    = (const float*)d_in[2];
    const float* proj = (const float*)d_in[3];
    float* out = (float*)d_out;

    float* S = (float*)d_ws;                       // NBH*C*M*D floats
    float* Z = S + (size_t)NBH * C_ * M_ * D_;     // NBH*C*M floats

    dim3 g1(C_, NBH);
    phase1_kernel<<<g1, dim3(512), 0, stream>>>(k, v, proj, S, Z);
    dim3 g2((M_ * D_ + M_) / 256, NBH);            // 65 x 16
    phase2_kernel<<<g2, dim3(256), 0, stream>>>(S, Z);
    phase3_kernel<<<g1, dim3(512), 0, stream>>>(q, k, v, proj, S, Z, out);
}

// Round 3
// 188.893 us; speedup vs baseline: 2.8253x; 2.8253x over previous
//
#include <hip/hip_runtime.h>

// Causal linear attention (Performer ReLU kernel) via chunked MFMA (bf16).
// B=2 L=4096 H=8 D=64 M=256 fp32 in/out. Chunk T=128, C=32, NBH=16.
// Phase1: Kp=relu(K.P^T) (MFMA), S_c = V^T.Kp [d][m], z_c = colsum(Kp).
// Phase2: exclusive prefix over chunks (unchanged).
// Phase3: Qp,Kp (MFMA); A=Qp.Kp^T masked; num = A.V + Qp.S_pre;
//         den = rowsum(A_masked) + Qp.z_pre; out = num/den.
// ws: S [NBH][C][D][M] fp32 (32 MB) then Z [NBH][C][M] (0.5 MB).
// NOTE: __launch_bounds__ 2nd arg acts as min BLOCKS/CU here (round-2
// post-mortem: (512,4) capped VGPR at 64 and spilled). (256,2) -> cap 256.

#define B_   2
#define L_   4096
#define H_   8
#define D_   64
#define M_   256
#define T_   128
#define C_   (L_ / T_)   // 32
#define NBH  (B_ * H_)   // 16
#define RATIO 0.0625f    // 1/sqrt(256)
#define STAB  0.001f
#define SQP  72          // Qp/Kp LDS row stride (bf16): 144B, 16B-aligned, 2-way banks
#define SAM  136         // Am/VT/KpT LDS row stride: 272B, 16B-aligned, 2-way banks

typedef __attribute__((ext_vector_type(8))) short short8;
typedef __attribute__((ext_vector_type(4))) float floatx4;

#define MFMA16(a, b, c) __builtin_amdgcn_mfma_f32_16x16x32_bf16(a, b, c, 0, 0, 0)

__device__ inline unsigned short f2bf(float x) {
    union { float f; unsigned u; } v; v.f = x;
    unsigned r = v.u + 0x7FFF + ((v.u >> 16) & 1);
    return (unsigned short)(r >> 16);
}
__device__ inline float bf2f(unsigned short b) {
    union { unsigned u; float f; } v; v.u = ((unsigned)b) << 16; return v.f;
}
// load 8 consecutive fp32 from global, round to 8 bf16 (one MFMA frag)
__device__ inline short8 ldg8_bf(const float* p) {
    float4 a = *(const float4*)p;
    float4 b = *(const float4*)(p + 4);
    short8 r;
    r[0] = (short)f2bf(a.x); r[1] = (short)f2bf(a.y);
    r[2] = (short)f2bf(a.z); r[3] = (short)f2bf(a.w);
    r[4] = (short)f2bf(b.x); r[5] = (short)f2bf(b.y);
    r[6] = (short)f2bf(b.z); r[7] = (short)f2bf(b.w);
    return r;
}

// ---------------- Phase 1: Kp, S_c = V^T.Kp, z_c ----------------
__global__ __launch_bounds__(256, 2)
void phase1_kernel(const float* __restrict__ key, const float* __restrict__ val,
                   const float* __restrict__ proj,
                   float* __restrict__ S, float* __restrict__ Z) {
    const int c = blockIdx.x, bh = blockIdx.y;
    const int b = bh / H_, h = bh % H_;
    const int tid = threadIdx.x;
    const int w = tid >> 6, lane = tid & 63;
    const int l15 = lane & 15, quad = lane >> 4;
    const int tb = 32 * w;

    __shared__ __align__(16) unsigned short VT[64 * SAM];   // V^T [d][t] bf16
    __shared__ __align__(16) unsigned short KpT[64 * SAM];  // Kp^T [m'][t] per fg

    const size_t rowstr = H_ * D_;
    const size_t base = ((size_t)b * L_ + (size_t)c * T_) * rowstr + (size_t)h * D_;

    // stage V transposed -> bf16
    for (int i = tid; i < T_ * 16; i += 256) {
        int t = i >> 4, d4 = (i & 15) * 4;
        float4 vv = *(const float4*)(val + base + (size_t)t * rowstr + d4);
        VT[(d4 + 0) * SAM + t] = f2bf(vv.x);
        VT[(d4 + 1) * SAM + t] = f2bf(vv.y);
        VT[(d4 + 2) * SAM + t] = f2bf(vv.z);
        VT[(d4 + 3) * SAM + t] = f2bf(vv.w);
    }
    // K A-frags: rows t = tb+rt*16+l15, k = d
    short8 kf[2][2];
#pragma unroll
    for (int rt = 0; rt < 2; ++rt)
#pragma unroll
        for (int kk = 0; kk < 2; ++kk)
            kf[rt][kk] = ldg8_bf(key + base + (size_t)(tb + rt * 16 + l15) * rowstr
                                 + kk * 32 + quad * 8);
    __syncthreads();
    // V^T A-frags: wave w owns d-rowtile w (rows d=16w..16w+16), k = t
    short8 vf[4];
#pragma unroll
    for (int k4 = 0; k4 < 4; ++k4)
        vf[k4] = *(const short8*)&VT[(16 * w + l15) * SAM + k4 * 32 + quad * 8];

    float* Sp = S + (size_t)(bh * C_ + c) * (M_ * D_);
    float* Zp = Z + (size_t)(bh * C_ + c) * M_;
    const int mloc = tid >> 2, q4 = tid & 3;

    for (int fg = 0; fg < 4; ++fg) {
        // P B-frags: n = m, k = d  (P[m][d] rows contiguous)
        short8 pf[4][2];
#pragma unroll
        for (int ct = 0; ct < 4; ++ct)
#pragma unroll
            for (int kk = 0; kk < 2; ++kk)
                pf[ct][kk] = ldg8_bf(proj + (size_t)(fg * 64 + ct * 16 + l15) * D_
                                     + kk * 32 + quad * 8);
        // Kp tiles = K . P^T
        floatx4 ck[2][4];
#pragma unroll
        for (int rt = 0; rt < 2; ++rt)
#pragma unroll
            for (int ct = 0; ct < 4; ++ct) {
                floatx4 z4 = {0.f, 0.f, 0.f, 0.f};
                z4 = MFMA16(kf[rt][0], pf[ct][0], z4);
                z4 = MFMA16(kf[rt][1], pf[ct][1], z4);
                ck[rt][ct] = z4;
            }
        __syncthreads();   // prev fg readers of KpT done
#pragma unroll
        for (int rt = 0; rt < 2; ++rt)
#pragma unroll
            for (int ct = 0; ct < 4; ++ct)
#pragma unroll
                for (int r = 0; r < 4; ++r) {
                    int t = tb + rt * 16 + quad * 4 + r;
                    int mp = ct * 16 + l15;
                    KpT[mp * SAM + t] =
                        f2bf(fmaxf(RATIO * ck[rt][ct][r], 0.f) + STAB);
                }
        __syncthreads();
        // S tiles: D[d][m] = V^T . Kp  (K-dim = t = 128)
        floatx4 sa[4];
#pragma unroll
        for (int ct = 0; ct < 4; ++ct) {
            floatx4 acc = {0.f, 0.f, 0.f, 0.f};
#pragma unroll
            for (int k4 = 0; k4 < 4; ++k4) {
                short8 kb = *(const short8*)&KpT[(ct * 16 + l15) * SAM
                                                + k4 * 32 + quad * 8];
                acc = MFMA16(vf[k4], kb, acc);
            }
            sa[ct] = acc;
        }
#pragma unroll
        for (int ct = 0; ct < 4; ++ct)
#pragma unroll
            for (int r = 0; r < 4; ++r)
                Sp[(size_t)(16 * w + quad * 4 + r) * M_
                   + fg * 64 + ct * 16 + l15] = sa[ct][r];
        // z[m] = sum_t Kp[t][m]  (KpT row m contiguous)
        {
            float zz = 0.f;
            const unsigned short* krow = &KpT[mloc * SAM + q4 * 32];
#pragma unroll
            for (int i = 0; i < 32; ++i) zz += bf2f(krow[i]);
            zz += __shfl_xor(zz, 1, 64);
            zz += __shfl_xor(zz, 2, 64);
            if (q4 == 0) Zp[fg * 64 + mloc] = zz;
        }
    }
}

// ---------------- Phase 2: exclusive prefix over chunks (in place) --------
__global__ void phase2_kernel(float* __restrict__ S, float* __restrict__ Z) {
    const int bh = blockIdx.y;
    const int j = blockIdx.x * 256 + threadIdx.x;
    if (j < M_ * D_) {
        float run = 0.f;
        float* p = S + (size_t)bh * C_ * M_ * D_ + j;
        for (int c = 0; c < C_; ++c) {
            float t = p[(size_t)c * (M_ * D_)];
            p[(size_t)c * (M_ * D_)] = run;
            run += t;
        }
    } else {
        const int j2 = j - M_ * D_;
        if (j2 < M_) {
            float run = 0.f;
            float* p = Z + (size_t)bh * C_ * M_ + j2;
            for (int c = 0; c < C_; ++c) {
                float t = p[c * M_];
                p[c * M_] = run;
                run += t;
            }
        }
    }
}

// ---------------- Phase 3: per-chunk output via MFMA ----------
__global__ __launch_bounds__(256, 2)
void phase3_kernel(const float* __restrict__ q, const float* __restrict__ key,
                   const float* __restrict__ val, const float* __restrict__ proj,
                   const float* __restrict__ S, const float* __restrict__ Z,
                   float* __restrict__ out) {
    const int c = blockIdx.x, bh = blockIdx.y;
    const int b = bh / H_, h = bh % H_;
    const int tid = threadIdx.x;
    const int w = tid >> 6, lane = tid & 63;
    const int l15 = lane & 15, quad = lane >> 4;
    const int tb = 32 * w;

    __shared__ __align__(16) unsigned short QK[2 * T_ * SQP];  // Qp|Kp; Am overlays
    __shared__ __align__(16) unsigned short VT[64 * SAM];
    __shared__ float zS[M_];
    __shared__ float denAS[T_];
    __shared__ float denZS[T_];

    unsigned short* QpL = QK;               // [t][m'] stride SQP
    unsigned short* KpL = QK + T_ * SQP;    // [t][m'] stride SQP
    unsigned short* AmL = QK;               // [t][tcol] stride SAM (overlay)

    const size_t rowstr = H_ * D_;
    const size_t base = ((size_t)b * L_ + (size_t)c * T_) * rowstr + (size_t)h * D_;
    const float* Sp = S + (size_t)(bh * C_ + c) * (M_ * D_);
    const float* Zp = Z + (size_t)(bh * C_ + c) * M_;

    // stage V^T (bf16) and z prefix
    for (int i = tid; i < T_ * 16; i += 256) {
        int t = i >> 4, d4 = (i & 15) * 4;
        float4 vv = *(const float4*)(val + base + (size_t)t * rowstr + d4);
        VT[(d4 + 0) * SAM + t] = f2bf(vv.x);
        VT[(d4 + 1) * SAM + t] = f2bf(vv.y);
        VT[(d4 + 2) * SAM + t] = f2bf(vv.z);
        VT[(d4 + 3) * SAM + t] = f2bf(vv.w);
    }
    zS[tid] = Zp[tid];
    // Q/K A-frags (persist across fg loop)
    short8 qf[2][2], kf[2][2];
#pragma unroll
    for (int rt = 0; rt < 2; ++rt)
#pragma unroll
        for (int kk = 0; kk < 2; ++kk) {
            size_t ro = base + (size_t)(tb + rt * 16 + l15) * rowstr + kk * 32 + quad * 8;
            qf[rt][kk] = ldg8_bf(q + ro);
            kf[rt][kk] = ldg8_bf(key + ro);
        }

    floatx4 Aacc[2][8];
    floatx4 num[2][4];
#pragma unroll
    for (int rt = 0; rt < 2; ++rt) {
#pragma unroll
        for (int ct = 0; ct < 8; ++ct) { floatx4 z4 = {0.f,0.f,0.f,0.f}; Aacc[rt][ct] = z4; }
#pragma unroll
        for (int dt = 0; dt < 4; ++dt) { floatx4 z4 = {0.f,0.f,0.f,0.f}; num[rt][dt] = z4; }
    }
    float denZacc = 0.f;
    const int tz = tid >> 1, hz = tid & 1;

    __syncthreads();   // VT/zS staged

    for (int fg = 0; fg < 4; ++fg) {
        // P B-frags (n = m, k = d)
        short8 pf[4][2];
#pragma unroll
        for (int ct = 0; ct < 4; ++ct)
#pragma unroll
            for (int kk = 0; kk < 2; ++kk)
                pf[ct][kk] = ldg8_bf(proj + (size_t)(fg * 64 + ct * 16 + l15) * D_
                                     + kk * 32 + quad * 8);
        // S_prefix B-frags (n = d, k = m): ws layout [d][m] -> 8 consec m
        short8 sf[4][2];
#pragma unroll
        for (int dt = 0; dt < 4; ++dt)
#pragma unroll
            for (int kk = 0; kk < 2; ++kk)
                sf[dt][kk] = ldg8_bf(Sp + (size_t)(dt * 16 + l15) * M_
                                     + fg * 64 + kk * 32 + quad * 8);
        // Qp/Kp tiles
        floatx4 cq[2][4], ck[2][4];
#pragma unroll
        for (int rt = 0; rt < 2; ++rt)
#pragma unroll
            for (int ct = 0; ct < 4; ++ct) {
                floatx4 a4 = {0.f,0.f,0.f,0.f};
                a4 = MFMA16(qf[rt][0], pf[ct][0], a4);
                a4 = MFMA16(qf[rt][1], pf[ct][1], a4);
                cq[rt][ct] = a4;
                floatx4 b4 = {0.f,0.f,0.f,0.f};
                b4 = MFMA16(kf[rt][0], pf[ct][0], b4);
                b4 = MFMA16(kf[rt][1], pf[ct][1], b4);
                ck[rt][ct] = b4;
            }
        __syncthreads();   // prev fg readers of Qp/Kp done
#pragma unroll
        for (int rt = 0; rt < 2; ++rt)
#pragma unroll
            for (int ct = 0; ct < 4; ++ct)
#pragma unroll
                for (int r = 0; r < 4; ++r) {
                    int t = tb + rt * 16 + quad * 4 + r;
                    int mp = ct * 16 + l15;
                    QpL[t * SQP + mp] = f2bf(fmaxf(RATIO * cq[rt][ct][r], 0.f) + STAB);
                    KpL[t * SQP + mp] = f2bf(fmaxf(RATIO * ck[rt][ct][r], 0.f) + STAB);
                }
        __syncthreads();
        // A += Qp.Kp^T  (K = m' 64);  num += Qp.S_fg
        short8 qa[2][2];
#pragma unroll
        for (int rt = 0; rt < 2; ++rt)
#pragma unroll
            for (int kk = 0; kk < 2; ++kk)
                qa[rt][kk] = *(const short8*)&QpL[(tb + rt * 16 + l15) * SQP
                                                 + kk * 32 + quad * 8];
#pragma unroll
        for (int ct = 0; ct < 8; ++ct) {
            short8 kb0 = *(const short8*)&KpL[(ct * 16 + l15) * SQP + quad * 8];
            short8 kb1 = *(const short8*)&KpL[(ct * 16 + l15) * SQP + 32 + quad * 8];
#pragma unroll
            for (int rt = 0; rt < 2; ++rt) {
                Aacc[rt][ct] = MFMA16(qa[rt][0], kb0, Aacc[rt][ct]);
                Aacc[rt][ct] = MFMA16(qa[rt][1], kb1, Aacc[rt][ct]);
            }
        }
#pragma unroll
        for (int dt = 0; dt < 4; ++dt)
#pragma unroll
            for (int rt = 0; rt < 2; ++rt) {
                num[rt][dt] = MFMA16(qa[rt][0], sf[dt][0], num[rt][dt]);
                num[rt][dt] = MFMA16(qa[rt][1], sf[dt][1], num[rt][dt]);
            }
        // denZ += Qp[tz][:] . z_fg  (intra-wave rows, post-barrier)
        {
            float dz = 0.f;
            const unsigned short* qrow = &QpL[tz * SQP + hz * 32];
            const float* zp = &zS[fg * 64 + hz * 32];
#pragma unroll
            for (int i = 0; i < 32; ++i) dz += bf2f(qrow[i]) * zp[i];
            dz += __shfl_xor(dz, 1, 64);
            denZacc += dz;
        }
    }

    // mask A (causal), rowsum -> denAS, cvt
    float drow[2][4];
#pragma unroll
    for (int rt = 0; rt < 2; ++rt)
#pragma unroll
        for (int r = 0; r < 4; ++r) drow[rt][r] = 0.f;
#pragma unroll
    for (int rt = 0; rt < 2; ++rt)
#pragma unroll
        for (int ct = 0; ct < 8; ++ct)
#pragma unroll
            for (int r = 0; r < 4; ++r) {
                int t = tb + rt * 16 + quad * 4 + r;
                int tc = ct * 16 + l15;
                float av = (tc <= t) ? Aacc[rt][ct][r] : 0.f;
                Aacc[rt][ct][r] = av;
                drow[rt][r] += av;
            }
#pragma unroll
    for (int rt = 0; rt < 2; ++rt)
#pragma unroll
        for (int r = 0; r < 4; ++r) {
            float s = drow[rt][r];
            s += __shfl_xor(s, 1, 64);
            s += __shfl_xor(s, 2, 64);
            s += __shfl_xor(s, 4, 64);
            s += __shfl_xor(s, 8, 64);
            drow[rt][r] = s;
        }
    __syncthreads();   // all fg readers of QpL/KpL done; Am overlays them
#pragma unroll
    for (int rt = 0; rt < 2; ++rt)
#pragma unroll
        for (int ct = 0; ct < 8; ++ct)
#pragma unroll
            for (int r = 0; r < 4; ++r) {
                int t = tb + rt * 16 + quad * 4 + r;
                AmL[t * SAM + ct * 16 + l15] = f2bf(Aacc[rt][ct][r]);
            }
    if (l15 == 0)
#pragma unroll
        for (int rt = 0; rt < 2; ++rt)
#pragma unroll
            for (int r = 0; r < 4; ++r)
                denAS[tb + rt * 16 + quad * 4 + r] = drow[rt][r];
    if (hz == 0) denZS[tz] = denZacc;
    __syncthreads();

    // num += A_masked . V   (K = tcol = 128)
    short8 am[2][4];
#pragma unroll
    for (int rt = 0; rt < 2; ++rt)
#pragma unroll
        for (int k4 = 0; k4 < 4; ++k4)
            am[rt][k4] = *(const short8*)&AmL[(tb + rt * 16 + l15) * SAM
                                             + k4 * 32 + quad * 8];
#pragma unroll
    for (int dt = 0; dt < 4; ++dt)
#pragma unroll
        for (int k4 = 0; k4 < 4; ++k4) {
            short8 vb = *(const short8*)&VT[(dt * 16 + l15) * SAM + k4 * 32 + quad * 8];
#pragma unroll
            for (int rt = 0; rt < 2; ++rt)
                num[rt][dt] = MFMA16(am[rt][k4], vb, num[rt][dt]);
        }

    // epilogue: out = num / den
#pragma unroll
    for (int rt = 0; rt < 2; ++rt)
#pragma unroll
        for (int r = 0; r < 4; ++r) {
            int t = tb + rt * 16 + quad * 4 + r;
            float den = denAS[t] + denZS[t];
            if (den <= 0.f) den = 1.f;
            float inv = 1.f / den;
#pragma unroll
            for (int dt = 0; dt < 4; ++dt)
                out[base + (size_t)t * rowstr + dt * 16 + l15] = num[rt][dt][r] * inv;
        }
}

extern "C" void kernel_launch(void* const* d_in, const int* in_sizes, int n_in,
                              void* d_out, int out_size, void* d_ws, size_t ws_size,
                              hipStream_t stream) {
    const float* q    = (const float*)d_in[0];
    const float* k    = (const float*)d_in[1];
    const float* v    = (const float*)d_in[2];
    const float* proj = (const float*)d_in[3];
    float* out = (float*)d_out;

    float* S = (float*)d_ws;                       // NBH*C*D*M floats
    float* Z = S + (size_t)NBH * C_ * M_ * D_;     // NBH*C*M floats

    dim3 g1(C_, NBH);
    phase1_kernel<<<g1, dim3(256), 0, stream>>>(k, v, proj, S, Z);
    dim3 g2((M_ * D_ + M_) / 256, NBH);            // 65 x 16
    phase2_kernel<<<g2, dim3(256), 0, stream>>>(S, Z);
    phase3_kernel<<<g1, dim3(256), 0, stream>>>(q, k, v, proj, S, Z, out);
}